// Round 1
// baseline (1885.768 us; speedup 1.0000x reference)
//
#include <hip/hip_runtime.h>
#include <hip/hip_bf16.h>

#define HIDDEN 768
#define NTOK   4096
#define SEQ    1024
#define NBATCH 4
#define NHEADS 12
#define KAUG   (HIDDEN * 9)   // 6912 = augmented K (silu + 8 spline bases per input dim)
#define NQKV   (3 * HIDDEN)   // 2304

using bf16 = __hip_bfloat16;
typedef __attribute__((ext_vector_type(4))) float f32x4;
typedef __attribute__((ext_vector_type(8))) short bf16x8;

__device__ inline void gload_lds16(const void* g, void* l) {
    __builtin_amdgcn_global_load_lds((const __attribute__((address_space(1))) void*)g,
                                     (__attribute__((address_space(3))) void*)l, 16, 0, 0);
}

// ---- Kernel 1: X_aug[n][i*9+0] = silu(x), [i*9+1..8] = cubic B-spline bases ----
__global__ void build_xaug(const float* __restrict__ x, bf16* __restrict__ xa) {
    int gid = blockIdx.x * blockDim.x + threadIdx.x;
    if (gid >= NTOK * HIDDEN) return;
    float xv = x[gid];
    int n = gid / HIDDEN;
    int i = gid - n * HIDDEN;
    float sil = xv / (1.0f + __expf(-xv));   // silu
    // grid[g] = (g-3)*0.4 - 1, g = 0..11
    float g[12];
#pragma unroll
    for (int k = 0; k < 12; ++k) g[k] = (float)(k - 3) * 0.4f - 1.0f;
    float b[11];
#pragma unroll
    for (int c = 0; c < 11; ++c) b[c] = (xv >= g[c] && xv < g[c + 1]) ? 1.0f : 0.0f;
#pragma unroll
    for (int k = 1; k <= 3; ++k) {
#pragma unroll
        for (int c = 0; c < 11; ++c) {
            if (c < 11 - k) {
                float left  = (xv - g[c]) / (g[c + k] - g[c]) * b[c];
                float right = (g[c + k + 1] - xv) / (g[c + k + 1] - g[c + 1]) * b[c + 1];
                b[c] = left + right;
            }
        }
    }
    bf16* dst = xa + (size_t)n * KAUG + (size_t)i * 9;
    dst[0] = __float2bfloat16(sil);
#pragma unroll
    for (int c = 0; c < 8; ++c) dst[1 + c] = __float2bfloat16(b[c]);
}

// ---- Kernel 2: W_aug rows for one projection: [base_w, spline_w*scaler] ----
__global__ void build_waug(const float* __restrict__ bw, const float* __restrict__ sw,
                           const float* __restrict__ sc, bf16* __restrict__ wa) {
    int gid = blockIdx.x * blockDim.x + threadIdx.x;
    if (gid >= HIDDEN * HIDDEN) return;
    int o = gid / HIDDEN;
    int i = gid - o * HIDDEN;
    float bwv = bw[gid];
    float scv = sc[gid];
    bf16* dst = wa + (size_t)o * KAUG + (size_t)i * 9;
    dst[0] = __float2bfloat16(bwv);
#pragma unroll
    for (int c = 0; c < 8; ++c)
        dst[1 + c] = __float2bfloat16(sw[(size_t)gid * 8 + c] * scv);
}

// ---- fp32 -> bf16 convert ----
__global__ void f2b(const float* __restrict__ in, bf16* __restrict__ out, int n) {
    int gid = blockIdx.x * blockDim.x + threadIdx.x;
    if (gid < n) out[gid] = __float2bfloat16(in[gid]);
}

// ---- Kernel 3/6: C[M][N] = A[M][K] @ B[N][K]^T (+bias), bf16 in, fp32 out ----
// m97 structure: 128x128 tile, BK=64, 4 waves, 16x16x32 bf16 MFMA, global_load_lds(16B)
__global__ __launch_bounds__(256) void gemm_bt(const bf16* __restrict__ A,
                                               const bf16* __restrict__ B,
                                               float* __restrict__ C,
                                               const float* __restrict__ bias,
                                               int M, int N, int K) {
    __shared__ __align__(16) bf16 As[128][64];
    __shared__ __align__(16) bf16 Bs[128][64];
    const int tid  = threadIdx.x;
    const int lane = tid & 63;
    const int wave = tid >> 6;
    const int wr = wave >> 1, wc = wave & 1;
    const int row0 = blockIdx.x * 128;
    const int col0 = blockIdx.y * 128;

    f32x4 acc[4][4];
#pragma unroll
    for (int m = 0; m < 4; ++m)
#pragma unroll
        for (int n = 0; n < 4; ++n) acc[m][n] = f32x4{0.f, 0.f, 0.f, 0.f};

    // staging: thread t loads 8 bf16 (16B); rows advance 32 per instruction
    const int srow = tid >> 3;
    const int scol = (tid & 7) * 8;
    const bf16* aptr = A + (size_t)(row0 + srow) * K + scol;
    const bf16* bptr = B + (size_t)(col0 + srow) * K + scol;
    char* adst = (char*)&As[0][0] + tid * 16;
    char* bdst = (char*)&Bs[0][0] + tid * 16;

    const int lr = lane & 15;          // fragment row
    const int lk = (lane >> 4) * 8;    // k-offset within 32

    for (int k0 = 0; k0 < K; k0 += 64) {
#pragma unroll
        for (int j = 0; j < 4; ++j)
            gload_lds16(aptr + (size_t)j * 32 * K + k0, adst + j * 4096);
#pragma unroll
        for (int j = 0; j < 4; ++j)
            gload_lds16(bptr + (size_t)j * 32 * K + k0, bdst + j * 4096);
        asm volatile("s_waitcnt vmcnt(0)" ::: "memory");
        __syncthreads();
#pragma unroll
        for (int kk = 0; kk < 64; kk += 32) {
            bf16x8 af[4], bfv[4];
#pragma unroll
            for (int m = 0; m < 4; ++m)
                af[m] = *(const bf16x8*)&As[wr * 64 + m * 16 + lr][kk + lk];
#pragma unroll
            for (int n = 0; n < 4; ++n)
                bfv[n] = *(const bf16x8*)&Bs[wc * 64 + n * 16 + lr][kk + lk];
#pragma unroll
            for (int m = 0; m < 4; ++m)
#pragma unroll
                for (int n = 0; n < 4; ++n)
                    acc[m][n] = __builtin_amdgcn_mfma_f32_16x16x32_bf16(af[m], bfv[n], acc[m][n], 0, 0, 0);
        }
        __syncthreads();
    }

    const int cr = (lane >> 4) * 4;
    const int cc = lane & 15;
#pragma unroll
    for (int m = 0; m < 4; ++m) {
#pragma unroll
        for (int n = 0; n < 4; ++n) {
            int c = col0 + wc * 64 + n * 16 + cc;
            float bv = bias ? bias[c] : 0.0f;
#pragma unroll
            for (int j = 0; j < 4; ++j) {
                int r = row0 + wr * 64 + m * 16 + cr + j;
                C[(size_t)r * N + c] = acc[m][n][j] + bv;
            }
        }
    }
}

// ---- Kernel 4: RoPE in place on Q (cols 0..767) and K (cols 768..1535) ----
__global__ void rope_kernel(float* __restrict__ qkv) {
    int gid = blockIdx.x * blockDim.x + threadIdx.x;
    if (gid >= NTOK * NHEADS * 32) return;
    int d = gid & 31;
    int h = (gid >> 5) % NHEADS;
    int n = gid / (32 * NHEADS);
    int s = n & (SEQ - 1);
    // inv_freq = 10000^(-d/32); ln(10000)/32 = 0.28782313662425574
    float inv = expf(-(float)d * 0.28782313662425574f);
    float th = (float)s * inv;
    float sn, cs;
    sincosf(th, &sn, &cs);
    size_t base = (size_t)n * NQKV + h * 64 + d;
    float q0 = qkv[base],       q1 = qkv[base + 32];
    qkv[base]       = q0 * cs - q1 * sn;
    qkv[base + 32]  = q1 * cs + q0 * sn;
    float k0 = qkv[base + 768], k1 = qkv[base + 800];
    qkv[base + 768] = k0 * cs - k1 * sn;
    qkv[base + 800] = k1 * cs + k0 * sn;
}

// ---- Kernel 5: attention, 1 thread per query row, online softmax (fp32) ----
__global__ __launch_bounds__(64) void attn_kernel(const float* __restrict__ qkv,
                                                  bf16* __restrict__ attn) {
    int bh = blockIdx.x;                  // 0..47
    int b = bh / NHEADS, h = bh - b * NHEADS;
    int q = blockIdx.y * 64 + threadIdx.x;
    int n = b * SEQ + q;
    const float* qrow = qkv + (size_t)n * NQKV + h * 64;
    float qreg[64];
#pragma unroll
    for (int d = 0; d < 64; ++d) qreg[d] = qrow[d] * 0.125f;   // 1/sqrt(64)
    const float* kbase = qkv + (size_t)b * SEQ * NQKV + 768 + h * 64;
    const float* vbase = kbase + 768;
    float acc[64];
#pragma unroll
    for (int d = 0; d < 64; ++d) acc[d] = 0.0f;
    float m = -3.0e38f, l = 0.0f;
    for (int kk = 0; kk < SEQ; ++kk) {
        const float* kr = kbase + (size_t)kk * NQKV;
        float s0 = 0.f, s1 = 0.f, s2 = 0.f, s3 = 0.f;
#pragma unroll
        for (int d = 0; d < 64; d += 4) {
            s0 = fmaf(qreg[d + 0], kr[d + 0], s0);
            s1 = fmaf(qreg[d + 1], kr[d + 1], s1);
            s2 = fmaf(qreg[d + 2], kr[d + 2], s2);
            s3 = fmaf(qreg[d + 3], kr[d + 3], s3);
        }
        float s = (s0 + s1) + (s2 + s3);
        float mn = fmaxf(m, s);
        if (__ballot(mn > m) != 0ull) {     // wave-uniform rescale branch
            float c = __expf(m - mn);       // ==1 for lanes with no new max
            l *= c;
#pragma unroll
            for (int d = 0; d < 64; ++d) acc[d] *= c;
            m = mn;
        }
        float e = __expf(s - m);
        l += e;
        const float* vr = vbase + (size_t)kk * NQKV;
#pragma unroll
        for (int d = 0; d < 64; ++d) acc[d] = fmaf(e, vr[d], acc[d]);
    }
    float invl = 1.0f / l;
    bf16* dst = attn + (size_t)n * HIDDEN + h * 64;
#pragma unroll
    for (int d = 0; d < 64; ++d) dst[d] = __float2bfloat16(acc[d] * invl);
}

extern "C" void kernel_launch(void* const* d_in, const int* in_sizes, int n_in,
                              void* d_out, int out_size, void* d_ws, size_t ws_size,
                              hipStream_t stream) {
    const float* x   = (const float*)d_in[0];
    const float* qbw = (const float*)d_in[1];
    const float* qsw = (const float*)d_in[2];
    const float* qsc = (const float*)d_in[3];
    const float* kbw = (const float*)d_in[4];
    const float* ksw = (const float*)d_in[5];
    const float* ksc = (const float*)d_in[6];
    const float* vbw = (const float*)d_in[7];
    const float* vsw = (const float*)d_in[8];
    const float* vsc = (const float*)d_in[9];
    const float* ow  = (const float*)d_in[10];
    const float* ob  = (const float*)d_in[11];

    char* ws = (char*)d_ws;
    size_t off = 0;
    bf16*  xaug  = (bf16*)(ws + off); off += (size_t)NTOK * KAUG * 2;     // 56.6 MB
    bf16*  waug  = (bf16*)(ws + off); off += (size_t)NQKV * KAUG * 2;     // 31.9 MB
    float* qkv   = (float*)(ws + off); off += (size_t)NTOK * NQKV * 4;    // 37.7 MB
    bf16*  attnb = (bf16*)(ws + off); off += (size_t)NTOK * HIDDEN * 2;   //  6.3 MB
    bf16*  owb   = (bf16*)(ws + off); off += (size_t)HIDDEN * HIDDEN * 2; //  1.2 MB
    if (off > ws_size) return;  // workspace too small: fail safely

    build_xaug<<<(NTOK * HIDDEN + 255) / 256, 256, 0, stream>>>(x, xaug);
    build_waug<<<(HIDDEN * HIDDEN + 255) / 256, 256, 0, stream>>>(qbw, qsw, qsc, waug);
    build_waug<<<(HIDDEN * HIDDEN + 255) / 256, 256, 0, stream>>>(kbw, ksw, ksc, waug + (size_t)HIDDEN * KAUG);
    build_waug<<<(HIDDEN * HIDDEN + 255) / 256, 256, 0, stream>>>(vbw, vsw, vsc, waug + (size_t)2 * HIDDEN * KAUG);
    f2b<<<(HIDDEN * HIDDEN + 255) / 256, 256, 0, stream>>>(ow, owb, HIDDEN * HIDDEN);

    gemm_bt<<<dim3(NTOK / 128, NQKV / 128), 256, 0, stream>>>(xaug, waug, qkv, nullptr, NTOK, NQKV, KAUG);
    rope_kernel<<<(NTOK * NHEADS * 32 + 255) / 256, 256, 0, stream>>>(qkv);
    attn_kernel<<<dim3(NBATCH * NHEADS, SEQ / 64), 64, 0, stream>>>(qkv, attnb);
    gemm_bt<<<dim3(NTOK / 128, HIDDEN / 128), 256, 0, stream>>>(attnb, owb, (float*)d_out, ob, NTOK, HIDDEN, HIDDEN);
}

// Round 2
// 472.751 us; speedup vs baseline: 3.9889x; 3.9889x over previous
//
#include <hip/hip_runtime.h>
#include <hip/hip_bf16.h>

#define HIDDEN 768
#define NTOK   4096
#define SEQ    1024
#define NBATCH 4
#define NHEADS 12
#define KAUG   (HIDDEN * 9)   // 6912
#define NQKV   (3 * HIDDEN)   // 2304

using bf16 = __hip_bfloat16;
typedef __attribute__((ext_vector_type(4))) float f32x4;
typedef __attribute__((ext_vector_type(8))) short bf16x8;

__device__ inline void gload_lds16(const void* g, void* l) {
    __builtin_amdgcn_global_load_lds((const __attribute__((address_space(1))) void*)g,
                                     (__attribute__((address_space(3))) void*)l, 16, 0, 0);
}

// ---- Kernel 1: X_aug[n][i*9+0] = silu(x), [i*9+1..8] = cubic B-spline bases ----
__global__ void build_xaug(const float* __restrict__ x, bf16* __restrict__ xa) {
    int gid = blockIdx.x * blockDim.x + threadIdx.x;
    if (gid >= NTOK * HIDDEN) return;
    float xv = x[gid];
    int n = gid / HIDDEN;
    int i = gid - n * HIDDEN;
    float sil = xv / (1.0f + __expf(-xv));
    float g[12];
#pragma unroll
    for (int k = 0; k < 12; ++k) g[k] = (float)(k - 3) * 0.4f - 1.0f;
    float b[11];
#pragma unroll
    for (int c = 0; c < 11; ++c) b[c] = (xv >= g[c] && xv < g[c + 1]) ? 1.0f : 0.0f;
#pragma unroll
    for (int k = 1; k <= 3; ++k) {
#pragma unroll
        for (int c = 0; c < 11; ++c) {
            if (c < 11 - k) {
                float left  = (xv - g[c]) / (g[c + k] - g[c]) * b[c];
                float right = (g[c + k + 1] - xv) / (g[c + k + 1] - g[c + 1]) * b[c + 1];
                b[c] = left + right;
            }
        }
    }
    bf16* dst = xa + (size_t)n * KAUG + (size_t)i * 9;
    dst[0] = __float2bfloat16(sil);
#pragma unroll
    for (int c = 0; c < 8; ++c) dst[1 + c] = __float2bfloat16(b[c]);
}

// ---- Kernel 2: W_aug rows: [base_w, spline_w*scaler] ----
__global__ void build_waug(const float* __restrict__ bw, const float* __restrict__ sw,
                           const float* __restrict__ sc, bf16* __restrict__ wa) {
    int gid = blockIdx.x * blockDim.x + threadIdx.x;
    if (gid >= HIDDEN * HIDDEN) return;
    float bwv = bw[gid];
    float scv = sc[gid];
    bf16* dst = wa + (size_t)gid * 9;
    dst[0] = __float2bfloat16(bwv);
#pragma unroll
    for (int c = 0; c < 8; ++c)
        dst[1 + c] = __float2bfloat16(sw[(size_t)gid * 8 + c] * scv);
}

__global__ void f2b(const float* __restrict__ in, bf16* __restrict__ out, int n) {
    int gid = blockIdx.x * blockDim.x + threadIdx.x;
    if (gid < n) out[gid] = __float2bfloat16(in[gid]);
}

// ---- GEMM: C[M][N] = A[M][K] @ B[N][K]^T (+bias), bf16 in, fp32 out ----
__global__ __launch_bounds__(256) void gemm_bt(const bf16* __restrict__ A,
                                               const bf16* __restrict__ B,
                                               float* __restrict__ C,
                                               const float* __restrict__ bias,
                                               int M, int N, int K) {
    __shared__ __align__(16) bf16 As[128][64];
    __shared__ __align__(16) bf16 Bs[128][64];
    const int tid  = threadIdx.x;
    const int lane = tid & 63;
    const int wave = tid >> 6;
    const int wr = wave >> 1, wc = wave & 1;
    const int row0 = blockIdx.x * 128;
    const int col0 = blockIdx.y * 128;

    f32x4 acc[4][4];
#pragma unroll
    for (int m = 0; m < 4; ++m)
#pragma unroll
        for (int n = 0; n < 4; ++n) acc[m][n] = f32x4{0.f, 0.f, 0.f, 0.f};

    const int srow = tid >> 3;
    const int scol = (tid & 7) * 8;
    const bf16* aptr = A + (size_t)(row0 + srow) * K + scol;
    const bf16* bptr = B + (size_t)(col0 + srow) * K + scol;
    char* adst = (char*)&As[0][0] + tid * 16;
    char* bdst = (char*)&Bs[0][0] + tid * 16;

    const int lr = lane & 15;
    const int lk = (lane >> 4) * 8;

    for (int k0 = 0; k0 < K; k0 += 64) {
#pragma unroll
        for (int j = 0; j < 4; ++j)
            gload_lds16(aptr + (size_t)j * 32 * K + k0, adst + j * 4096);
#pragma unroll
        for (int j = 0; j < 4; ++j)
            gload_lds16(bptr + (size_t)j * 32 * K + k0, bdst + j * 4096);
        asm volatile("s_waitcnt vmcnt(0)" ::: "memory");
        __syncthreads();
#pragma unroll
        for (int kk = 0; kk < 64; kk += 32) {
            bf16x8 af[4], bfv[4];
#pragma unroll
            for (int m = 0; m < 4; ++m)
                af[m] = *(const bf16x8*)&As[wr * 64 + m * 16 + lr][kk + lk];
#pragma unroll
            for (int n = 0; n < 4; ++n)
                bfv[n] = *(const bf16x8*)&Bs[wc * 64 + n * 16 + lr][kk + lk];
#pragma unroll
            for (int m = 0; m < 4; ++m)
#pragma unroll
                for (int n = 0; n < 4; ++n)
                    acc[m][n] = __builtin_amdgcn_mfma_f32_16x16x32_bf16(af[m], bfv[n], acc[m][n], 0, 0, 0);
        }
        __syncthreads();
    }

    const int cr = (lane >> 4) * 4;
    const int cc = lane & 15;
#pragma unroll
    for (int m = 0; m < 4; ++m) {
#pragma unroll
        for (int n = 0; n < 4; ++n) {
            int c = col0 + wc * 64 + n * 16 + cc;
            float bv = bias ? bias[c] : 0.0f;
#pragma unroll
            for (int j = 0; j < 4; ++j) {
                int r = row0 + wr * 64 + m * 16 + cr + j;
                C[(size_t)r * N + c] = acc[m][n][j] + bv;
            }
        }
    }
}

// ---- RoPE + head-major bf16 repack: qb/kb/vb [b*H+h][s][64]; q pre-scaled 1/8 ----
__global__ void rope_bf16(const float* __restrict__ qkv, bf16* __restrict__ qb,
                          bf16* __restrict__ kb, bf16* __restrict__ vb) {
    int gid = blockIdx.x * blockDim.x + threadIdx.x;
    if (gid >= NTOK * NHEADS * 32) return;
    int d = gid & 31;
    int h = (gid >> 5) % NHEADS;
    int n = gid / (32 * NHEADS);
    int s = n & (SEQ - 1);
    int b = n >> 10;
    float inv = __expf(-(float)d * 0.28782313662425574f);  // 10000^(-d/32)
    float th = (float)s * inv;
    float sn, cs;
    sincosf(th, &sn, &cs);
    size_t src = (size_t)n * NQKV + h * 64 + d;
    float q0 = qkv[src],        q1 = qkv[src + 32];
    float k0 = qkv[src + 768],  k1 = qkv[src + 800];
    float v0 = qkv[src + 1536], v1 = qkv[src + 1568];
    size_t dst = ((size_t)(b * NHEADS + h) * SEQ + s) * 64 + d;
    qb[dst]      = __float2bfloat16((q0 * cs - q1 * sn) * 0.125f);
    qb[dst + 32] = __float2bfloat16((q1 * cs + q0 * sn) * 0.125f);
    kb[dst]      = __float2bfloat16(k0 * cs - k1 * sn);
    kb[dst + 32] = __float2bfloat16(k1 * cs + k0 * sn);
    vb[dst]      = __float2bfloat16(v0);
    vb[dst + 32] = __float2bfloat16(v1);
}

// ---- MFMA flash attention: block = (b,h, 64-row q-tile), 4 waves x 16 q-rows ----
__global__ __launch_bounds__(256) void attn_mfma(const bf16* __restrict__ qb,
                                                 const bf16* __restrict__ kb,
                                                 const bf16* __restrict__ vb,
                                                 bf16* __restrict__ attnb) {
    __shared__ __align__(16) bf16 Kls[64][64];   // [k][d]
    __shared__ __align__(16) bf16 Vt[64][64];    // [d][k]
    __shared__ __align__(16) bf16 Pls[4][16][64];

    const int tid  = threadIdx.x;
    const int lane = tid & 63;
    const int w    = tid >> 6;
    const int bh   = blockIdx.x;
    const int b    = bh / NHEADS, h = bh - b * NHEADS;
    const int qt   = blockIdx.y;

    const bf16* qhead = qb + (size_t)bh * SEQ * 64;
    const bf16* khead = kb + (size_t)bh * SEQ * 64;
    const bf16* vhead = vb + (size_t)bh * SEQ * 64;

    const int lr = lane & 15;
    const int lg = lane >> 4;

    bf16x8 qf[2];
    {
        const bf16* qrow = qhead + (size_t)(qt * 64 + w * 16 + lr) * 64 + lg * 8;
        qf[0] = *(const bf16x8*)qrow;
        qf[1] = *(const bf16x8*)(qrow + 32);
    }

    f32x4 oacc[4];
#pragma unroll
    for (int n = 0; n < 4; ++n) oacc[n] = f32x4{0.f, 0.f, 0.f, 0.f};
    float mrun[4], lrun[4];
#pragma unroll
    for (int j = 0; j < 4; ++j) { mrun[j] = -3.0e38f; lrun[j] = 0.0f; }

    for (int t = 0; t < SEQ / 64; ++t) {
        {   // K tile: 8KB via 2x global_load_lds(16B)
            const char* src = (const char*)(khead + (size_t)t * 64 * 64);
            char* dst = (char*)&Kls[0][0];
            gload_lds16(src + tid * 16, dst + tid * 16);
            gload_lds16(src + 4096 + tid * 16, dst + 4096 + tid * 16);
        }
        {   // V tile transposed into Vt[d][k]
            int r = tid & 63, g = tid >> 6;
            const bf16* vrow = vhead + (size_t)(t * 64 + r) * 64 + g * 16;
            bf16x8 v0 = *(const bf16x8*)vrow;
            bf16x8 v1 = *(const bf16x8*)(vrow + 8);
#pragma unroll
            for (int jj = 0; jj < 8; ++jj) {
                Vt[g * 16 + jj][r]     = ((const bf16*)&v0)[jj];
                Vt[g * 16 + 8 + jj][r] = ((const bf16*)&v1)[jj];
            }
        }
        asm volatile("s_waitcnt vmcnt(0)" ::: "memory");
        __syncthreads();

        // S = Q . K^T  (C layout: row q = lg*4+j, col k = n*16+lr)
        f32x4 sacc[4];
#pragma unroll
        for (int n = 0; n < 4; ++n) sacc[n] = f32x4{0.f, 0.f, 0.f, 0.f};
#pragma unroll
        for (int c = 0; c < 2; ++c)
#pragma unroll
            for (int n = 0; n < 4; ++n) {
                bf16x8 kf = *(const bf16x8*)&Kls[n * 16 + lr][c * 32 + lg * 8];
                sacc[n] = __builtin_amdgcn_mfma_f32_16x16x32_bf16(qf[c], kf, sacc[n], 0, 0, 0);
            }

        // online softmax, rows j = 0..3 per lane
        float pj[4][4];
#pragma unroll
        for (int j = 0; j < 4; ++j) {
            float mx = fmaxf(fmaxf(sacc[0][j], sacc[1][j]), fmaxf(sacc[2][j], sacc[3][j]));
            mx = fmaxf(mx, __shfl_xor(mx, 1));
            mx = fmaxf(mx, __shfl_xor(mx, 2));
            mx = fmaxf(mx, __shfl_xor(mx, 4));
            mx = fmaxf(mx, __shfl_xor(mx, 8));
            float mnew = fmaxf(mrun[j], mx);
            float csc = __expf(mrun[j] - mnew);
            mrun[j] = mnew;
            float sum = 0.f;
#pragma unroll
            for (int n = 0; n < 4; ++n) {
                float p = __expf(sacc[n][j] - mnew);
                pj[n][j] = p;
                sum += p;
            }
            sum += __shfl_xor(sum, 1);
            sum += __shfl_xor(sum, 2);
            sum += __shfl_xor(sum, 4);
            sum += __shfl_xor(sum, 8);
            lrun[j] = lrun[j] * csc + sum;
#pragma unroll
            for (int n = 0; n < 4; ++n) oacc[n][j] *= csc;
        }

        // P -> LDS (wave-private), then PV
#pragma unroll
        for (int n = 0; n < 4; ++n)
#pragma unroll
            for (int j = 0; j < 4; ++j)
                Pls[w][lg * 4 + j][n * 16 + lr] = __float2bfloat16(pj[n][j]);

#pragma unroll
        for (int c = 0; c < 2; ++c) {
            bf16x8 pf = *(const bf16x8*)&Pls[w][lr][c * 32 + lg * 8];
#pragma unroll
            for (int n = 0; n < 4; ++n) {
                bf16x8 vf = *(const bf16x8*)&Vt[n * 16 + lr][c * 32 + lg * 8];
                oacc[n] = __builtin_amdgcn_mfma_f32_16x16x32_bf16(pf, vf, oacc[n], 0, 0, 0);
            }
        }
        __syncthreads();
    }

#pragma unroll
    for (int j = 0; j < 4; ++j) {
        float invl = 1.0f / lrun[j];
        int tok = b * SEQ + qt * 64 + w * 16 + lg * 4 + j;
        bf16* dst = attnb + (size_t)tok * HIDDEN + h * 64;
#pragma unroll
        for (int n = 0; n < 4; ++n)
            dst[n * 16 + lr] = __float2bfloat16(oacc[n][j] * invl);
    }
}

extern "C" void kernel_launch(void* const* d_in, const int* in_sizes, int n_in,
                              void* d_out, int out_size, void* d_ws, size_t ws_size,
                              hipStream_t stream) {
    const float* x   = (const float*)d_in[0];
    const float* qbw = (const float*)d_in[1];
    const float* qsw = (const float*)d_in[2];
    const float* qsc = (const float*)d_in[3];
    const float* kbw = (const float*)d_in[4];
    const float* ksw = (const float*)d_in[5];
    const float* ksc = (const float*)d_in[6];
    const float* vbw = (const float*)d_in[7];
    const float* vsw = (const float*)d_in[8];
    const float* vsc = (const float*)d_in[9];
    const float* ow  = (const float*)d_in[10];
    const float* ob  = (const float*)d_in[11];

    char* ws = (char*)d_ws;
    size_t off = 0;
    bf16*  xaug = (bf16*)(ws + off); off += (size_t)NTOK * KAUG * 2;   // 56.6 MB
    bf16*  waug = (bf16*)(ws + off); off += (size_t)NQKV * KAUG * 2;   // 31.9 MB
    float* qkv  = (float*)(ws + off); off += (size_t)NTOK * NQKV * 4;  // 37.7 MB
    if (off > ws_size) return;

    // dead-region aliases (valid by launch order):
    //  - xaug dead after GEMM1 -> attnb (6.3MB) + owb (at +8MB)
    //  - waug dead after GEMM1 -> qb/kb/vb (3 x 6.3MB)
    bf16* attnb = xaug;
    bf16* owb   = (bf16*)((char*)xaug + (8u << 20));
    const size_t headsz = (size_t)NTOK * 64 * NHEADS;  // elements per tensor
    bf16* qb = waug;
    bf16* kb = waug + headsz;
    bf16* vb = waug + 2 * headsz;

    build_xaug<<<(NTOK * HIDDEN + 255) / 256, 256, 0, stream>>>(x, xaug);
    build_waug<<<(HIDDEN * HIDDEN + 255) / 256, 256, 0, stream>>>(qbw, qsw, qsc, waug);
    build_waug<<<(HIDDEN * HIDDEN + 255) / 256, 256, 0, stream>>>(kbw, ksw, ksc, waug + (size_t)HIDDEN * KAUG);
    build_waug<<<(HIDDEN * HIDDEN + 255) / 256, 256, 0, stream>>>(vbw, vsw, vsc, waug + (size_t)2 * HIDDEN * KAUG);

    gemm_bt<<<dim3(NTOK / 128, NQKV / 128), 256, 0, stream>>>(xaug, waug, qkv, nullptr, NTOK, NQKV, KAUG);

    f2b<<<(HIDDEN * HIDDEN + 255) / 256, 256, 0, stream>>>(ow, owb, HIDDEN * HIDDEN);
    rope_bf16<<<(NTOK * NHEADS * 32 + 255) / 256, 256, 0, stream>>>(qkv, qb, kb, vb);
    attn_mfma<<<dim3(NBATCH * NHEADS, SEQ / 64), 256, 0, stream>>>(qb, kb, vb, attnb);
    gemm_bt<<<dim3(NTOK / 128, HIDDEN / 128), 256, 0, stream>>>(attnb, owb, (float*)d_out, ob, NTOK, HIDDEN, HIDDEN);
}